// Round 1
// baseline (843.218 us; speedup 1.0000x reference)
//
#include <hip/hip_runtime.h>
#include <cmath>

// Transformer block (ViT): LN1 -> QKV -> MHA -> proj(+res) -> LN2 -> FC1+GELU -> FC2(+res)
// B=16, N=577, C=1024, H=16, D=64, HIDDEN=4096. fp32 in/out, fp16 MFMA compute.

#define MTOK 9232            // 16*577 valid token rows
#define MPAD 9344            // 73*128, padded for 128-row GEMM tiles
#define SEQ  577

typedef _Float16 half8  __attribute__((ext_vector_type(8)));
typedef _Float16 half4  __attribute__((ext_vector_type(4)));
typedef float    float4v __attribute__((ext_vector_type(4)));

__device__ __forceinline__ void gl_lds16(const void* g, void* l) {
  // async global->LDS, 16B per lane, LDS dest = wave-uniform base + lane*16
  __builtin_amdgcn_global_load_lds((const __attribute__((address_space(1))) void*)g,
                                   (__attribute__((address_space(3))) void*)l, 16, 0, 0);
}

// ---------------- fp32 -> fp16 convert (weights) ----------------
__global__ __launch_bounds__(256) void cvt_f16_kernel(const float* __restrict__ in,
                                                      _Float16* __restrict__ out, int n) {
  int i = (blockIdx.x * 256 + threadIdx.x) * 8;
  if (i >= n) return;
  float4v a = *(const float4v*)(in + i);
  float4v b = *(const float4v*)(in + i + 4);
  half8 o = { (_Float16)a[0], (_Float16)a[1], (_Float16)a[2], (_Float16)a[3],
              (_Float16)b[0], (_Float16)b[1], (_Float16)b[2], (_Float16)b[3] };
  *(half8*)(out + i) = o;
}

// ---------------- LayerNorm: fp32 in -> fp16 out, pad rows zeroed ----------------
__global__ __launch_bounds__(256) void ln_kernel(const float* __restrict__ x,
                                                 const float* __restrict__ gam,
                                                 const float* __restrict__ bet,
                                                 _Float16* __restrict__ out, int mrows) {
  int row = blockIdx.x, t = threadIdx.x;
  _Float16* orow = out + (long)row * 1024 + t * 4;
  if (row >= mrows) { half4 z = {}; *(half4*)orow = z; return; }
  float4v xv = *(const float4v*)(x + (long)row * 1024 + t * 4);
  float s  = xv[0] + xv[1] + xv[2] + xv[3];
  float ss = xv[0]*xv[0] + xv[1]*xv[1] + xv[2]*xv[2] + xv[3]*xv[3];
  #pragma unroll
  for (int o = 32; o > 0; o >>= 1) { s += __shfl_down(s, o); ss += __shfl_down(ss, o); }
  __shared__ float red[8];
  int w = t >> 6;
  if ((t & 63) == 0) { red[w] = s; red[4 + w] = ss; }
  __syncthreads();
  s  = red[0] + red[1] + red[2] + red[3];
  ss = red[4] + red[5] + red[6] + red[7];
  float mean = s * (1.0f / 1024.0f);
  float var  = ss * (1.0f / 1024.0f) - mean * mean;
  float rstd = rsqrtf(var + 1e-5f);
  float4v gv = *(const float4v*)(gam + t * 4);
  float4v bv = *(const float4v*)(bet + t * 4);
  half4 o;
  #pragma unroll
  for (int i = 0; i < 4; i++) o[i] = (_Float16)((xv[i] - mean) * rstd * gv[i] + bv[i]);
  *(half4*)orow = o;
}

// ---------------- GEMM: C[m,n] = sum_k A[m,k]*B[n,k] (+bias, epilogue) ----------------
// A: [MPAD][K] fp16, B: [N][K] fp16 (weights row-major = B^T layout). 128x128 tile,
// BK=64, 4 waves in 2x2, each wave 4x4 tiles of 16x16x32 MFMA. m97 structure.
// EPI: 0 = bias -> fp16 out; 1 = bias+GELU(exact) -> fp16 out; 2 = bias+res -> fp32 out (m<MTOK)
template <int EPI>
__global__ __launch_bounds__(256) void gemm_bt(const _Float16* __restrict__ A,
                                               const _Float16* __restrict__ Bw,
                                               const float* __restrict__ bias,
                                               const float* __restrict__ res,
                                               void* __restrict__ outv, int Ndim, int K) {
  __shared__ __align__(16) _Float16 As[128 * 64];
  __shared__ __align__(16) _Float16 Bs[128 * 64];
  int mt = blockIdx.x, nt = blockIdx.y;
  int t = threadIdx.x, w = t >> 6, l = t & 63;
  int wm = (w >> 1) * 64, wn = (w & 1) * 64;
  int g = l >> 4, li = l & 15;
  float4v acc[4][4] = {};
  const _Float16* aBase = A  + (long)mt * 128 * K;
  const _Float16* bBase = Bw + (long)nt * 128 * K;
  int nk = K >> 6;
  for (int kt = 0; kt < nk; ++kt) {
    const _Float16* ak = aBase + kt * 64;
    const _Float16* bk = bBase + kt * 64;
    #pragma unroll
    for (int r = 0; r < 4; ++r) {
      int idx = (w * 4 + r) * 64 + l;       // 16B chunk id: row=idx>>3, kchunk=idx&7
      int row = idx >> 3, kc = idx & 7;
      gl_lds16(ak + (long)row * K + kc * 8, As + (w * 4 + r) * 512);
      gl_lds16(bk + (long)row * K + kc * 8, Bs + (w * 4 + r) * 512);
    }
    __syncthreads();
    #pragma unroll
    for (int ks = 0; ks < 2; ++ks) {
      half8 af[4], bf[4];
      #pragma unroll
      for (int i = 0; i < 4; i++)
        af[i] = *(const half8*)(As + (wm + i * 16 + li) * 64 + ks * 32 + g * 8);
      #pragma unroll
      for (int j = 0; j < 4; j++)
        bf[j] = *(const half8*)(Bs + (wn + j * 16 + li) * 64 + ks * 32 + g * 8);
      #pragma unroll
      for (int i = 0; i < 4; i++)
        #pragma unroll
        for (int j = 0; j < 4; j++)
          acc[i][j] = __builtin_amdgcn_mfma_f32_16x16x32_f16(af[i], bf[j], acc[i][j], 0, 0, 0);
    }
    __syncthreads();
  }
  // epilogue: C/D layout col=lane&15, row=(lane>>4)*4+reg
  #pragma unroll
  for (int j = 0; j < 4; ++j) {
    int col = nt * 128 + wn + j * 16 + li;
    float bsv = bias[col];
    #pragma unroll
    for (int i = 0; i < 4; ++i) {
      int row0 = mt * 128 + wm + i * 16 + g * 4;
      #pragma unroll
      for (int r = 0; r < 4; ++r) {
        int row = row0 + r;
        float v = acc[i][j][r] + bsv;
        if (EPI == 0) {
          ((_Float16*)outv)[(long)row * Ndim + col] = (_Float16)v;
        } else if (EPI == 1) {
          float ge = 0.5f * v * (1.0f + erff(v * 0.70710678118654752f));
          ((_Float16*)outv)[(long)row * Ndim + col] = (_Float16)ge;
        } else {
          if (row < MTOK) {
            ((float*)outv)[(long)row * Ndim + col] = v + res[(long)row * Ndim + col];
          }
        }
      }
    }
  }
}

// ---------------- Fused attention: softmax(Q K^T * s) V per (b,h) ----------------
// Block = 64 q-rows of one (b,h); wave = 16 q-rows. Key tiles of 32, online softmax.
// QK^T and PV via 16x16x32 MFMA; P round-trips through per-wave LDS (C->A layout).
__global__ __launch_bounds__(256) void attn_kernel(const _Float16* __restrict__ qkv,
                                                   _Float16* __restrict__ Y) {
  int qt = blockIdx.x, bh = blockIdx.y;
  int b = bh >> 4, h = bh & 15;
  int t = threadIdx.x, w = t >> 6, l = t & 63;
  int g = l >> 4, li = l & 15;
  __shared__ __align__(16) _Float16 Vt[2][64 * 40];  // V transposed [d][key], stride 40
  __shared__ __align__(16) _Float16 Pl[4][16 * 40];  // per-wave P [qrow][key], stride 40
  long base = (long)b * SEQ;
  int qrow = qt * 64 + w * 16 + li;                  // may run into pad rows (buffer padded)
  const _Float16* qp = qkv + (base + qrow) * 3072 + h * 64;
  half8 qf0 = *(const half8*)(qp + g * 8);           // A-frag k=0..31
  half8 qf1 = *(const half8*)(qp + 32 + g * 8);      // A-frag k=32..63
  float4v o[4] = {};
  float mrow[4] = { -1e30f, -1e30f, -1e30f, -1e30f };
  float lrow[4] = {};
  const int NKT = 19;                                // 19*32 = 608 >= 577
  int vkr = t >> 3, vdb = (t & 7) * 8;
  { // stage V tile 0 (transposed)
    const _Float16* vp = qkv + (base + vkr) * 3072 + 2048 + h * 64 + vdb;
    half8 vv = *(const half8*)vp;
    #pragma unroll
    for (int i = 0; i < 8; i++) Vt[0][(vdb + i) * 40 + vkr] = vv[i];
  }
  __syncthreads();
  for (int kt = 0; kt < NKT; ++kt) {
    int buf = kt & 1;
    if (kt + 1 < NKT) { // prefetch next V tile into other buffer
      const _Float16* vp = qkv + (base + (kt + 1) * 32 + vkr) * 3072 + 2048 + h * 64 + vdb;
      half8 vv = *(const half8*)vp;
      #pragma unroll
      for (int i = 0; i < 8; i++) Vt[buf ^ 1][(vdb + i) * 40 + vkr] = vv[i];
    }
    int key0 = kt * 32;
    float4v s0 = {}, s1 = {};
    const _Float16* kp0 = qkv + (base + key0 + li) * 3072 + 1024 + h * 64;
    const _Float16* kp1 = kp0 + 16 * 3072;
    half8 kf00 = *(const half8*)(kp0 + g * 8);
    half8 kf01 = *(const half8*)(kp0 + 32 + g * 8);
    half8 kf10 = *(const half8*)(kp1 + g * 8);
    half8 kf11 = *(const half8*)(kp1 + 32 + g * 8);
    s0 = __builtin_amdgcn_mfma_f32_16x16x32_f16(qf0, kf00, s0, 0, 0, 0);
    s0 = __builtin_amdgcn_mfma_f32_16x16x32_f16(qf1, kf01, s0, 0, 0, 0);
    s1 = __builtin_amdgcn_mfma_f32_16x16x32_f16(qf0, kf10, s1, 0, 0, 0);
    s1 = __builtin_amdgcn_mfma_f32_16x16x32_f16(qf1, kf11, s1, 0, 0, 0);
    bool msk0 = (key0 + li) >= SEQ;
    bool msk1 = (key0 + 16 + li) >= SEQ;
    float alpha[4];
    #pragma unroll
    for (int r = 0; r < 4; ++r) {
      float v0 = msk0 ? -1e30f : s0[r] * 0.125f;
      float v1 = msk1 ? -1e30f : s1[r] * 0.125f;
      float mx = fmaxf(v0, v1);
      mx = fmaxf(mx, __shfl_xor(mx, 1));
      mx = fmaxf(mx, __shfl_xor(mx, 2));
      mx = fmaxf(mx, __shfl_xor(mx, 4));
      mx = fmaxf(mx, __shfl_xor(mx, 8));
      float mn = fmaxf(mrow[r], mx);
      float al = __expf(mrow[r] - mn);
      float p0 = __expf(v0 - mn);
      float p1 = __expf(v1 - mn);
      float rs = p0 + p1;
      rs += __shfl_xor(rs, 1);
      rs += __shfl_xor(rs, 2);
      rs += __shfl_xor(rs, 4);
      rs += __shfl_xor(rs, 8);
      lrow[r] = lrow[r] * al + rs;
      mrow[r] = mn;
      alpha[r] = al;
      Pl[w][(g * 4 + r) * 40 + li]      = (_Float16)p0;   // C-layout -> LDS
      Pl[w][(g * 4 + r) * 40 + 16 + li] = (_Float16)p1;
    }
    #pragma unroll
    for (int dt = 0; dt < 4; ++dt)
      #pragma unroll
      for (int r = 0; r < 4; ++r) o[dt][r] *= alpha[r];
    half8 pf = *(const half8*)(&Pl[w][li * 40 + g * 8]);  // A-layout read-back
    #pragma unroll
    for (int dt = 0; dt < 4; ++dt) {
      half8 vf = *(const half8*)(&Vt[buf][(dt * 16 + li) * 40 + g * 8]); // B-frag
      o[dt] = __builtin_amdgcn_mfma_f32_16x16x32_f16(pf, vf, o[dt], 0, 0, 0);
    }
    __syncthreads();
  }
  #pragma unroll
  for (int r = 0; r < 4; ++r) {
    int qr = qt * 64 + w * 16 + g * 4 + r;
    if (qr < SEQ) {
      float inv = 1.0f / lrow[r];
      _Float16* yp = Y + (base + qr) * 1024 + h * 64 + li;
      #pragma unroll
      for (int dt = 0; dt < 4; ++dt) yp[dt * 16] = (_Float16)(o[dt][r] * inv);
    }
  }
}

extern "C" void kernel_launch(void* const* d_in, const int* in_sizes, int n_in,
                              void* d_out, int out_size, void* d_ws, size_t ws_size,
                              hipStream_t stream) {
  (void)in_sizes; (void)n_in; (void)out_size; (void)ws_size;
  const float* x      = (const float*)d_in[0];
  const float* w_qkv  = (const float*)d_in[1];
  const float* b_qkv  = (const float*)d_in[2];
  const float* w_proj = (const float*)d_in[3];
  const float* b_proj = (const float*)d_in[4];
  const float* ln1_g  = (const float*)d_in[5];
  const float* ln1_b  = (const float*)d_in[6];
  const float* ln2_g  = (const float*)d_in[7];
  const float* ln2_b  = (const float*)d_in[8];
  const float* w_fc1  = (const float*)d_in[9];
  const float* b_fc1  = (const float*)d_in[10];
  const float* w_fc2  = (const float*)d_in[11];
  const float* b_fc2  = (const float*)d_in[12];

  // workspace layout (bytes), total 159,121,408
  char* ws = (char*)d_ws;
  _Float16* Abuf = (_Float16*)ws;                          // [MPAD][1024] act fp16 (xn1 / xn2)
  _Float16* Wq   = (_Float16*)(ws + 19136512);             // weights fp16
  _Float16* Wp   = Wq + 3072 * 1024;
  _Float16* W1   = Wp + 1024 * 1024;
  _Float16* W2   = W1 + 4096 * 1024;
  _Float16* Qb   = (_Float16*)(ws + 44302336);             // [MPAD][3072] qkv fp16
  _Float16* Yb   = Qb + (long)MPAD * 3072;                 // [MPAD][1024] attn out fp16
  _Float16* Hb   = Qb;                                     // [MPAD][4096] fp16, reuses Qb+Yb
  float*    X1   = (float*)(ws + 120848384);               // [MPAD][1024] fp32 x+attn

  cvt_f16_kernel<<<1536, 256, 0, stream>>>(w_qkv, Wq, 3072 * 1024);
  cvt_f16_kernel<<<512,  256, 0, stream>>>(w_proj, Wp, 1024 * 1024);
  cvt_f16_kernel<<<2048, 256, 0, stream>>>(w_fc1, W1, 4096 * 1024);
  cvt_f16_kernel<<<2048, 256, 0, stream>>>(w_fc2, W2, 4096 * 1024);

  ln_kernel<<<MPAD, 256, 0, stream>>>(x, ln1_g, ln1_b, Abuf, MTOK);
  gemm_bt<0><<<dim3(73, 24), 256, 0, stream>>>(Abuf, Wq, b_qkv, nullptr, Qb, 3072, 1024);
  attn_kernel<<<dim3(10, 256), 256, 0, stream>>>(Qb, Yb);
  gemm_bt<2><<<dim3(73, 8), 256, 0, stream>>>(Yb, Wp, b_proj, x, X1, 1024, 1024);
  ln_kernel<<<MPAD, 256, 0, stream>>>(X1, ln2_g, ln2_b, Abuf, MTOK);
  gemm_bt<1><<<dim3(73, 32), 256, 0, stream>>>(Abuf, W1, b_fc1, nullptr, Hb, 4096, 1024);
  gemm_bt<2><<<dim3(73, 8), 256, 0, stream>>>(Hb, W2, b_fc2, X1, d_out, 1024, 4096);
}

// Round 2
// 705.291 us; speedup vs baseline: 1.1956x; 1.1956x over previous
//
#include <hip/hip_runtime.h>
#include <cmath>

// Transformer block (ViT): LN1 -> QKV -> MHA -> proj(+res) -> LN2 -> FC1+GELU -> FC2(+res)
// B=16, N=577, C=1024, H=16, D=64, HIDDEN=4096. fp32 in/out, fp16 MFMA compute.
// R1: XOR-swizzled LDS K-chunk placement to kill 16-way bank conflicts on ds_read_b128.

#define MTOK 9232            // 16*577 valid token rows
#define MPAD 9344            // 73*128, padded for 128-row GEMM tiles
#define SEQ  577

typedef _Float16 half8  __attribute__((ext_vector_type(8)));
typedef _Float16 half4  __attribute__((ext_vector_type(4)));
typedef float    float4v __attribute__((ext_vector_type(4)));

__device__ __forceinline__ void gl_lds16(const void* g, void* l) {
  // async global->LDS, 16B per lane, LDS dest = wave-uniform base + lane*16
  __builtin_amdgcn_global_load_lds((const __attribute__((address_space(1))) void*)g,
                                   (__attribute__((address_space(3))) void*)l, 16, 0, 0);
}

// ---------------- fp32 -> fp16 convert (weights) ----------------
__global__ __launch_bounds__(256) void cvt_f16_kernel(const float* __restrict__ in,
                                                      _Float16* __restrict__ out, int n) {
  int i = (blockIdx.x * 256 + threadIdx.x) * 8;
  if (i >= n) return;
  float4v a = *(const float4v*)(in + i);
  float4v b = *(const float4v*)(in + i + 4);
  half8 o = { (_Float16)a[0], (_Float16)a[1], (_Float16)a[2], (_Float16)a[3],
              (_Float16)b[0], (_Float16)b[1], (_Float16)b[2], (_Float16)b[3] };
  *(half8*)(out + i) = o;
}

// ---------------- LayerNorm: fp32 in -> fp16 out, pad rows zeroed ----------------
__global__ __launch_bounds__(256) void ln_kernel(const float* __restrict__ x,
                                                 const float* __restrict__ gam,
                                                 const float* __restrict__ bet,
                                                 _Float16* __restrict__ out, int mrows) {
  int row = blockIdx.x, t = threadIdx.x;
  _Float16* orow = out + (long)row * 1024 + t * 4;
  if (row >= mrows) { half4 z = {}; *(half4*)orow = z; return; }
  float4v xv = *(const float4v*)(x + (long)row * 1024 + t * 4);
  float s  = xv[0] + xv[1] + xv[2] + xv[3];
  float ss = xv[0]*xv[0] + xv[1]*xv[1] + xv[2]*xv[2] + xv[3]*xv[3];
  #pragma unroll
  for (int o = 32; o > 0; o >>= 1) { s += __shfl_down(s, o); ss += __shfl_down(ss, o); }
  __shared__ float red[8];
  int w = t >> 6;
  if ((t & 63) == 0) { red[w] = s; red[4 + w] = ss; }
  __syncthreads();
  s  = red[0] + red[1] + red[2] + red[3];
  ss = red[4] + red[5] + red[6] + red[7];
  float mean = s * (1.0f / 1024.0f);
  float var  = ss * (1.0f / 1024.0f) - mean * mean;
  float rstd = rsqrtf(var + 1e-5f);
  float4v gv = *(const float4v*)(gam + t * 4);
  float4v bv = *(const float4v*)(bet + t * 4);
  half4 o;
  #pragma unroll
  for (int i = 0; i < 4; i++) o[i] = (_Float16)((xv[i] - mean) * rstd * gv[i] + bv[i]);
  *(half4*)orow = o;
}

// ---------------- GEMM: C[m,n] = sum_k A[m,k]*B[n,k] (+bias, epilogue) ----------------
// A: [MPAD][K] fp16, B: [N][K] fp16 (weights row-major = B^T layout). 128x128 tile,
// BK=64, 4 waves in 2x2, each wave 4x4 tiles of 16x16x32 MFMA. m97 structure.
// LDS layout: row-major 128x64, but 16B chunk at physical slot p of row r holds
// global chunk p ^ (r&7) — XOR swizzle so fragment reads spread across banks.
// EPI: 0 = bias -> fp16 out; 1 = bias+GELU(exact) -> fp16 out; 2 = bias+res -> fp32 out (m<MTOK)
template <int EPI>
__global__ __launch_bounds__(256) void gemm_bt(const _Float16* __restrict__ A,
                                               const _Float16* __restrict__ Bw,
                                               const float* __restrict__ bias,
                                               const float* __restrict__ res,
                                               void* __restrict__ outv, int Ndim, int K) {
  __shared__ __align__(16) _Float16 As[128 * 64];
  __shared__ __align__(16) _Float16 Bs[128 * 64];
  int mt = blockIdx.x, nt = blockIdx.y;
  int t = threadIdx.x, w = t >> 6, l = t & 63;
  int wm = (w >> 1) * 64, wn = (w & 1) * 64;
  int g = l >> 4, li = l & 15;
  float4v acc[4][4] = {};
  const _Float16* aBase = A  + (long)mt * 128 * K;
  const _Float16* bBase = Bw + (long)nt * 128 * K;
  int nk = K >> 6;
  for (int kt = 0; kt < nk; ++kt) {
    const _Float16* ak = aBase + kt * 64;
    const _Float16* bk = bBase + kt * 64;
    #pragma unroll
    for (int r = 0; r < 4; ++r) {
      int idx = (w * 4 + r) * 64 + l;       // physical 16B slot id within the tile
      int row = idx >> 3;
      int kc  = (idx & 7) ^ (row & 7);      // XOR swizzle: slot p holds chunk p^(row&7)
      gl_lds16(ak + (long)row * K + kc * 8, As + (w * 4 + r) * 512);
      gl_lds16(bk + (long)row * K + kc * 8, Bs + (w * 4 + r) * 512);
    }
    __syncthreads();
    #pragma unroll
    for (int ks = 0; ks < 2; ++ks) {
      half8 af[4], bf[4];
      #pragma unroll
      for (int i = 0; i < 4; i++) {
        int ar = wm + i * 16 + li;
        af[i] = *(const half8*)(As + ar * 64 + (((ks * 4 + g) ^ (ar & 7)) * 8));
      }
      #pragma unroll
      for (int j = 0; j < 4; j++) {
        int br = wn + j * 16 + li;
        bf[j] = *(const half8*)(Bs + br * 64 + (((ks * 4 + g) ^ (br & 7)) * 8));
      }
      #pragma unroll
      for (int i = 0; i < 4; i++)
        #pragma unroll
        for (int j = 0; j < 4; j++)
          acc[i][j] = __builtin_amdgcn_mfma_f32_16x16x32_f16(af[i], bf[j], acc[i][j], 0, 0, 0);
    }
    __syncthreads();
  }
  // epilogue: C/D layout col=lane&15, row=(lane>>4)*4+reg
  #pragma unroll
  for (int j = 0; j < 4; ++j) {
    int col = nt * 128 + wn + j * 16 + li;
    float bsv = bias[col];
    #pragma unroll
    for (int i = 0; i < 4; ++i) {
      int row0 = mt * 128 + wm + i * 16 + g * 4;
      #pragma unroll
      for (int r = 0; r < 4; ++r) {
        int row = row0 + r;
        float v = acc[i][j][r] + bsv;
        if (EPI == 0) {
          ((_Float16*)outv)[(long)row * Ndim + col] = (_Float16)v;
        } else if (EPI == 1) {
          float ge = 0.5f * v * (1.0f + erff(v * 0.70710678118654752f));
          ((_Float16*)outv)[(long)row * Ndim + col] = (_Float16)ge;
        } else {
          if (row < MTOK) {
            ((float*)outv)[(long)row * Ndim + col] = v + res[(long)row * Ndim + col];
          }
        }
      }
    }
  }
}

// ---------------- Fused attention: softmax(Q K^T * s) V per (b,h) ----------------
// Block = 64 q-rows of one (b,h); wave = 16 q-rows. Key tiles of 32, online softmax.
// QK^T and PV via 16x16x32 MFMA; P round-trips through per-wave LDS (C->A layout).
__global__ __launch_bounds__(256) void attn_kernel(const _Float16* __restrict__ qkv,
                                                   _Float16* __restrict__ Y) {
  int qt = blockIdx.x, bh = blockIdx.y;
  int b = bh >> 4, h = bh & 15;
  int t = threadIdx.x, w = t >> 6, l = t & 63;
  int g = l >> 4, li = l & 15;
  __shared__ __align__(16) _Float16 Vt[2][64 * 40];  // V transposed [d][key], stride 40
  __shared__ __align__(16) _Float16 Pl[4][16 * 40];  // per-wave P [qrow][key], stride 40
  long base = (long)b * SEQ;
  int qrow = qt * 64 + w * 16 + li;                  // may run into pad rows (buffer padded)
  const _Float16* qp = qkv + (base + qrow) * 3072 + h * 64;
  half8 qf0 = *(const half8*)(qp + g * 8);           // A-frag k=0..31
  half8 qf1 = *(const half8*)(qp + 32 + g * 8);      // A-frag k=32..63
  float4v o[4] = {};
  float mrow[4] = { -1e30f, -1e30f, -1e30f, -1e30f };
  float lrow[4] = {};
  const int NKT = 19;                                // 19*32 = 608 >= 577
  int vkr = t >> 3, vdb = (t & 7) * 8;
  { // stage V tile 0 (transposed)
    const _Float16* vp = qkv + (base + vkr) * 3072 + 2048 + h * 64 + vdb;
    half8 vv = *(const half8*)vp;
    #pragma unroll
    for (int i = 0; i < 8; i++) Vt[0][(vdb + i) * 40 + vkr] = vv[i];
  }
  __syncthreads();
  for (int kt = 0; kt < NKT; ++kt) {
    int buf = kt & 1;
    if (kt + 1 < NKT) { // prefetch next V tile into other buffer
      const _Float16* vp = qkv + (base + (kt + 1) * 32 + vkr) * 3072 + 2048 + h * 64 + vdb;
      half8 vv = *(const half8*)vp;
      #pragma unroll
      for (int i = 0; i < 8; i++) Vt[buf ^ 1][(vdb + i) * 40 + vkr] = vv[i];
    }
    int key0 = kt * 32;
    float4v s0 = {}, s1 = {};
    const _Float16* kp0 = qkv + (base + key0 + li) * 3072 + 1024 + h * 64;
    const _Float16* kp1 = kp0 + 16 * 3072;
    half8 kf00 = *(const half8*)(kp0 + g * 8);
    half8 kf01 = *(const half8*)(kp0 + 32 + g * 8);
    half8 kf10 = *(const half8*)(kp1 + g * 8);
    half8 kf11 = *(const half8*)(kp1 + 32 + g * 8);
    s0 = __builtin_amdgcn_mfma_f32_16x16x32_f16(qf0, kf00, s0, 0, 0, 0);
    s0 = __builtin_amdgcn_mfma_f32_16x16x32_f16(qf1, kf01, s0, 0, 0, 0);
    s1 = __builtin_amdgcn_mfma_f32_16x16x32_f16(qf0, kf10, s1, 0, 0, 0);
    s1 = __builtin_amdgcn_mfma_f32_16x16x32_f16(qf1, kf11, s1, 0, 0, 0);
    bool msk0 = (key0 + li) >= SEQ;
    bool msk1 = (key0 + 16 + li) >= SEQ;
    float alpha[4];
    #pragma unroll
    for (int r = 0; r < 4; ++r) {
      float v0 = msk0 ? -1e30f : s0[r] * 0.125f;
      float v1 = msk1 ? -1e30f : s1[r] * 0.125f;
      float mx = fmaxf(v0, v1);
      mx = fmaxf(mx, __shfl_xor(mx, 1));
      mx = fmaxf(mx, __shfl_xor(mx, 2));
      mx = fmaxf(mx, __shfl_xor(mx, 4));
      mx = fmaxf(mx, __shfl_xor(mx, 8));
      float mn = fmaxf(mrow[r], mx);
      float al = __expf(mrow[r] - mn);
      float p0 = __expf(v0 - mn);
      float p1 = __expf(v1 - mn);
      float rs = p0 + p1;
      rs += __shfl_xor(rs, 1);
      rs += __shfl_xor(rs, 2);
      rs += __shfl_xor(rs, 4);
      rs += __shfl_xor(rs, 8);
      lrow[r] = lrow[r] * al + rs;
      mrow[r] = mn;
      alpha[r] = al;
      Pl[w][(g * 4 + r) * 40 + li]      = (_Float16)p0;   // C-layout -> LDS
      Pl[w][(g * 4 + r) * 40 + 16 + li] = (_Float16)p1;
    }
    #pragma unroll
    for (int dt = 0; dt < 4; ++dt)
      #pragma unroll
      for (int r = 0; r < 4; ++r) o[dt][r] *= alpha[r];
    half8 pf = *(const half8*)(&Pl[w][li * 40 + g * 8]);  // A-layout read-back
    #pragma unroll
    for (int dt = 0; dt < 4; ++dt) {
      half8 vf = *(const half8*)(&Vt[buf][(dt * 16 + li) * 40 + g * 8]); // B-frag
      o[dt] = __builtin_amdgcn_mfma_f32_16x16x32_f16(pf, vf, o[dt], 0, 0, 0);
    }
    __syncthreads();
  }
  #pragma unroll
  for (int r = 0; r < 4; ++r) {
    int qr = qt * 64 + w * 16 + g * 4 + r;
    if (qr < SEQ) {
      float inv = 1.0f / lrow[r];
      _Float16* yp = Y + (base + qr) * 1024 + h * 64 + li;
      #pragma unroll
      for (int dt = 0; dt < 4; ++dt) yp[dt * 16] = (_Float16)(o[dt][r] * inv);
    }
  }
}

extern "C" void kernel_launch(void* const* d_in, const int* in_sizes, int n_in,
                              void* d_out, int out_size, void* d_ws, size_t ws_size,
                              hipStream_t stream) {
  (void)in_sizes; (void)n_in; (void)out_size; (void)ws_size;
  const float* x      = (const float*)d_in[0];
  const float* w_qkv  = (const float*)d_in[1];
  const float* b_qkv  = (const float*)d_in[2];
  const float* w_proj = (const float*)d_in[3];
  const float* b_proj = (const float*)d_in[4];
  const float* ln1_g  = (const float*)d_in[5];
  const float* ln1_b  = (const float*)d_in[6];
  const float* ln2_g  = (const float*)d_in[7];
  const float* ln2_b  = (const float*)d_in[8];
  const float* w_fc1  = (const float*)d_in[9];
  const float* b_fc1  = (const float*)d_in[10];
  const float* w_fc2  = (const float*)d_in[11];
  const float* b_fc2  = (const float*)d_in[12];

  // workspace layout (bytes), total 159,121,408
  char* ws = (char*)d_ws;
  _Float16* Abuf = (_Float16*)ws;                          // [MPAD][1024] act fp16 (xn1 / xn2)
  _Float16* Wq   = (_Float16*)(ws + 19136512);             // weights fp16
  _Float16* Wp   = Wq + 3072 * 1024;
  _Float16* W1   = Wp + 1024 * 1024;
  _Float16* W2   = W1 + 4096 * 1024;
  _Float16* Qb   = (_Float16*)(ws + 44302336);             // [MPAD][3072] qkv fp16
  _Float16* Yb   = Qb + (long)MPAD * 3072;                 // [MPAD][1024] attn out fp16
  _Float16* Hb   = Qb;                                     // [MPAD][4096] fp16, reuses Qb+Yb
  float*    X1   = (float*)(ws + 120848384);               // [MPAD][1024] fp32 x+attn

  cvt_f16_kernel<<<1536, 256, 0, stream>>>(w_qkv, Wq, 3072 * 1024);
  cvt_f16_kernel<<<512,  256, 0, stream>>>(w_proj, Wp, 1024 * 1024);
  cvt_f16_kernel<<<2048, 256, 0, stream>>>(w_fc1, W1, 4096 * 1024);
  cvt_f16_kernel<<<2048, 256, 0, stream>>>(w_fc2, W2, 4096 * 1024);

  ln_kernel<<<MPAD, 256, 0, stream>>>(x, ln1_g, ln1_b, Abuf, MTOK);
  gemm_bt<0><<<dim3(73, 24), 256, 0, stream>>>(Abuf, Wq, b_qkv, nullptr, Qb, 3072, 1024);
  attn_kernel<<<dim3(10, 256), 256, 0, stream>>>(Qb, Yb);
  gemm_bt<2><<<dim3(73, 8), 256, 0, stream>>>(Yb, Wp, b_proj, x, X1, 1024, 1024);
  ln_kernel<<<MPAD, 256, 0, stream>>>(X1, ln2_g, ln2_b, Abuf, MTOK);
  gemm_bt<1><<<dim3(73, 32), 256, 0, stream>>>(Abuf, W1, b_fc1, nullptr, Hb, 4096, 1024);
  gemm_bt<2><<<dim3(73, 8), 256, 0, stream>>>(Hb, W2, b_fc2, X1, d_out, 1024, 4096);
}

// Round 3
// 639.894 us; speedup vs baseline: 1.3177x; 1.1022x over previous
//
#include <hip/hip_runtime.h>
#include <cmath>

// Transformer block (ViT): LN1 -> QKV -> MHA -> proj(+res) -> LN2 -> FC1+GELU -> FC2(+res)
// B=16, N=577, C=1024, H=16, D=64, HIDDEN=4096. fp32 in/out, fp16 MFMA compute.
// R1: XOR-swizzled LDS K-chunk placement to kill 16-way bank conflicts on ds_read_b128.
// R2: attention rewrite — V pre-transposed in global, K/V tiles staged via global_load_lds
//     with XOR swizzle, 64-key tiles, 32 q-rows/wave, exp2-domain softmax.
//     GELU exact-erf -> tanh form (1 exp2 + rcp), saves ~1400 VALU instr/wave in fc1.

#define MTOK 9232            // 16*577 valid token rows
#define MPAD 9344            // 73*128, padded for 128-row GEMM tiles
#define SEQ  577
#define SEQP 640             // 10*64 padded key count
#define NKT  10

typedef _Float16 half8  __attribute__((ext_vector_type(8)));
typedef _Float16 half4  __attribute__((ext_vector_type(4)));
typedef float    float4v __attribute__((ext_vector_type(4)));

__device__ __forceinline__ void gl_lds16(const void* g, void* l) {
  // async global->LDS, 16B per lane, LDS dest = wave-uniform base + lane*16
  __builtin_amdgcn_global_load_lds((const __attribute__((address_space(1))) void*)g,
                                   (__attribute__((address_space(3))) void*)l, 16, 0, 0);
}

__device__ __forceinline__ float fexp2(float x) { return __builtin_amdgcn_exp2f(x); }
__device__ __forceinline__ float frcp(float x)  { return __builtin_amdgcn_rcpf(x); }

// ---------------- fp32 -> fp16 convert (weights) ----------------
__global__ __launch_bounds__(256) void cvt_f16_kernel(const float* __restrict__ in,
                                                      _Float16* __restrict__ out, int n) {
  int i = (blockIdx.x * 256 + threadIdx.x) * 8;
  if (i >= n) return;
  float4v a = *(const float4v*)(in + i);
  float4v b = *(const float4v*)(in + i + 4);
  half8 o = { (_Float16)a[0], (_Float16)a[1], (_Float16)a[2], (_Float16)a[3],
              (_Float16)b[0], (_Float16)b[1], (_Float16)b[2], (_Float16)b[3] };
  *(half8*)(out + i) = o;
}

// ---------------- LayerNorm: fp32 in -> fp16 out, pad rows zeroed ----------------
__global__ __launch_bounds__(256) void ln_kernel(const float* __restrict__ x,
                                                 const float* __restrict__ gam,
                                                 const float* __restrict__ bet,
                                                 _Float16* __restrict__ out, int mrows) {
  int row = blockIdx.x, t = threadIdx.x;
  _Float16* orow = out + (long)row * 1024 + t * 4;
  if (row >= mrows) { half4 z = {}; *(half4*)orow = z; return; }
  float4v xv = *(const float4v*)(x + (long)row * 1024 + t * 4);
  float s  = xv[0] + xv[1] + xv[2] + xv[3];
  float ss = xv[0]*xv[0] + xv[1]*xv[1] + xv[2]*xv[2] + xv[3]*xv[3];
  #pragma unroll
  for (int o = 32; o > 0; o >>= 1) { s += __shfl_down(s, o); ss += __shfl_down(ss, o); }
  __shared__ float red[8];
  int w = t >> 6;
  if ((t & 63) == 0) { red[w] = s; red[4 + w] = ss; }
  __syncthreads();
  s  = red[0] + red[1] + red[2] + red[3];
  ss = red[4] + red[5] + red[6] + red[7];
  float mean = s * (1.0f / 1024.0f);
  float var  = ss * (1.0f / 1024.0f) - mean * mean;
  float rstd = rsqrtf(var + 1e-5f);
  float4v gv = *(const float4v*)(gam + t * 4);
  float4v bv = *(const float4v*)(bet + t * 4);
  half4 o;
  #pragma unroll
  for (int i = 0; i < 4; i++) o[i] = (_Float16)((xv[i] - mean) * rstd * gv[i] + bv[i]);
  *(half4*)orow = o;
}

// ---------------- GEMM: C[m,n] = sum_k A[m,k]*B[n,k] (+bias, epilogue) ----------------
// A: [MPAD][K] fp16, B: [N][K] fp16 (weights row-major = B^T layout). 128x128 tile,
// BK=64, 4 waves in 2x2, each wave 4x4 tiles of 16x16x32 MFMA. m97 structure.
// LDS layout: row-major 128x64, 16B chunk at physical slot p of row r holds
// global chunk p ^ (r&7) — XOR swizzle so fragment reads spread across banks.
// EPI: 0 = bias -> fp16 out; 1 = bias+GELU(tanh) -> fp16 out; 2 = bias+res -> fp32 out (m<MTOK)
template <int EPI>
__global__ __launch_bounds__(256) void gemm_bt(const _Float16* __restrict__ A,
                                               const _Float16* __restrict__ Bw,
                                               const float* __restrict__ bias,
                                               const float* __restrict__ res,
                                               void* __restrict__ outv, int Ndim, int K) {
  __shared__ __align__(16) _Float16 As[128 * 64];
  __shared__ __align__(16) _Float16 Bs[128 * 64];
  int mt = blockIdx.x, nt = blockIdx.y;
  int t = threadIdx.x, w = t >> 6, l = t & 63;
  int wm = (w >> 1) * 64, wn = (w & 1) * 64;
  int g = l >> 4, li = l & 15;
  float4v acc[4][4] = {};
  const _Float16* aBase = A  + (long)mt * 128 * K;
  const _Float16* bBase = Bw + (long)nt * 128 * K;
  int nk = K >> 6;
  for (int kt = 0; kt < nk; ++kt) {
    const _Float16* ak = aBase + kt * 64;
    const _Float16* bk = bBase + kt * 64;
    #pragma unroll
    for (int r = 0; r < 4; ++r) {
      int idx = (w * 4 + r) * 64 + l;       // physical 16B slot id within the tile
      int row = idx >> 3;
      int kc  = (idx & 7) ^ (row & 7);      // XOR swizzle: slot p holds chunk p^(row&7)
      gl_lds16(ak + (long)row * K + kc * 8, As + (w * 4 + r) * 512);
      gl_lds16(bk + (long)row * K + kc * 8, Bs + (w * 4 + r) * 512);
    }
    __syncthreads();
    #pragma unroll
    for (int ks = 0; ks < 2; ++ks) {
      half8 af[4], bf[4];
      #pragma unroll
      for (int i = 0; i < 4; i++) {
        int ar = wm + i * 16 + li;
        af[i] = *(const half8*)(As + ar * 64 + (((ks * 4 + g) ^ (ar & 7)) * 8));
      }
      #pragma unroll
      for (int j = 0; j < 4; j++) {
        int br = wn + j * 16 + li;
        bf[j] = *(const half8*)(Bs + br * 64 + (((ks * 4 + g) ^ (br & 7)) * 8));
      }
      #pragma unroll
      for (int i = 0; i < 4; i++)
        #pragma unroll
        for (int j = 0; j < 4; j++)
          acc[i][j] = __builtin_amdgcn_mfma_f32_16x16x32_f16(af[i], bf[j], acc[i][j], 0, 0, 0);
    }
    __syncthreads();
  }
  // epilogue: C/D layout col=lane&15, row=(lane>>4)*4+reg
  #pragma unroll
  for (int j = 0; j < 4; ++j) {
    int col = nt * 128 + wn + j * 16 + li;
    float bsv = bias[col];
    #pragma unroll
    for (int i = 0; i < 4; ++i) {
      int row0 = mt * 128 + wm + i * 16 + g * 4;
      #pragma unroll
      for (int r = 0; r < 4; ++r) {
        int row = row0 + r;
        float v = acc[i][j][r] + bsv;
        if (EPI == 0) {
          ((_Float16*)outv)[(long)row * Ndim + col] = (_Float16)v;
        } else if (EPI == 1) {
          // tanh-GELU: v * sigmoid(2*0.7978845608*(v + 0.044715 v^3))
          float y = v * (0.79788456f + 0.035677408f * v * v);
          float ge = v * frcp(1.0f + fexp2(-2.88539008f * y));
          ((_Float16*)outv)[(long)row * Ndim + col] = (_Float16)ge;
        } else {
          if (row < MTOK) {
            ((float*)outv)[(long)row * Ndim + col] = v + res[(long)row * Ndim + col];
          }
        }
      }
    }
  }
}

// ---------------- V transpose: Qb V-part [key][d] -> Vt [bh][d][SEQP] fp16 ----------------
__global__ __launch_bounds__(256) void vt_kernel(const _Float16* __restrict__ qkv,
                                                 _Float16* __restrict__ Vt) {
  int kt = blockIdx.x, bh = blockIdx.y;
  int b = bh >> 4, h = bh & 15;
  long base = (long)b * SEQ;
  __shared__ _Float16 Lt[64][72];
  int t = threadIdx.x;
  #pragma unroll
  for (int c = t; c < 512; c += 256) {
    int key = c >> 3, dc = c & 7;
    int kglob = kt * 64 + key;
    half8 v = {};
    if (kglob < SEQ) v = *(const half8*)(qkv + (base + kglob) * 3072 + 2048 + h * 64 + dc * 8);
    *(half8*)(&Lt[key][dc * 8]) = v;
  }
  __syncthreads();
  #pragma unroll
  for (int c = t; c < 512; c += 256) {
    int d = c >> 3, kc = c & 7;
    half8 o;
    #pragma unroll
    for (int j = 0; j < 8; j++) o[j] = Lt[kc * 8 + j][d];
    *(half8*)(Vt + ((long)bh * 64 + d) * SEQP + kt * 64 + kc * 8) = o;
  }
}

// ---------------- Fused attention v2 ----------------
// Block = 128 q-rows of one (b,h), 4 waves, wave = 32 q-rows. 64-key tiles.
// K tile staged from qkv (rows=keys), V tile from Vt (rows=d), both gl_lds16+XOR swizzle.
// Online softmax in exp2 domain; P via per-wave padded LDS (C->A layout round trip).
__global__ __launch_bounds__(256) void attn_kernel(const _Float16* __restrict__ qkv,
                                                   const _Float16* __restrict__ Vt,
                                                   _Float16* __restrict__ Y) {
  int qt = blockIdx.x, bh = blockIdx.y;
  int b = bh >> 4, h = bh & 15;
  long base = (long)b * SEQ;
  int t = threadIdx.x, w = t >> 6, l = t & 63;
  int g = l >> 4, li = l & 15;
  __shared__ __align__(16) _Float16 Ks[64 * 64];
  __shared__ __align__(16) _Float16 Vs[64 * 64];
  __shared__ __align__(16) _Float16 Pw[4][32 * 72];
  int q0 = qt * 128 + w * 32;
  half8 qf[2][2];
  #pragma unroll
  for (int m = 0; m < 2; ++m)
    #pragma unroll
    for (int ks = 0; ks < 2; ++ks)
      qf[m][ks] = *(const half8*)(qkv + (base + q0 + m * 16 + li) * 3072 + h * 64 + ks * 32 + g * 8);
  float4v o[2][4] = {};
  float mrow[2][4] = { { -1e30f, -1e30f, -1e30f, -1e30f }, { -1e30f, -1e30f, -1e30f, -1e30f } };
  float lrow[2][4] = {};
  const _Float16* vtb = Vt + (long)bh * 64 * SEQP;
  for (int kt = 0; kt < NKT; ++kt) {
    // stage K (8 KB) + V (8 KB): 512 chunks each, 2 rounds of 256 lanes
    #pragma unroll
    for (int rr = 0; rr < 2; ++rr) {
      int idx = rr * 256 + w * 64 + l;
      int row = idx >> 3;
      int kc  = (idx & 7) ^ (row & 7);
      gl_lds16(qkv + (base + kt * 64 + row) * 3072 + 1024 + h * 64 + kc * 8,
               Ks + (rr * 256 + w * 64) * 8);
      gl_lds16(vtb + (long)row * SEQP + kt * 64 + kc * 8,
               Vs + (rr * 256 + w * 64) * 8);
    }
    __syncthreads();
    // S = Q K^T  (m: 2 q-tiles, n: 4 key-tiles, k = 64)
    float4v s[2][4] = {};
    #pragma unroll
    for (int ks = 0; ks < 2; ++ks) {
      #pragma unroll
      for (int n = 0; n < 4; ++n) {
        int kr = n * 16 + li;
        half8 kf = *(const half8*)(Ks + kr * 64 + (((ks * 4 + g) ^ (kr & 7)) * 8));
        s[0][n] = __builtin_amdgcn_mfma_f32_16x16x32_f16(qf[0][ks], kf, s[0][n], 0, 0, 0);
        s[1][n] = __builtin_amdgcn_mfma_f32_16x16x32_f16(qf[1][ks], kf, s[1][n], 0, 0, 0);
      }
    }
    // online softmax (exp2 domain): scale = 0.125 * log2(e)
    bool last = (kt == NKT - 1);
    const float sc = 0.125f * 1.44269504f;
    #pragma unroll
    for (int m = 0; m < 2; ++m) {
      #pragma unroll
      for (int r = 0; r < 4; ++r) {
        float v[4];
        #pragma unroll
        for (int n = 0; n < 4; ++n) {
          v[n] = s[m][n][r] * sc;
          if (last && (kt * 64 + n * 16 + li) >= SEQ) v[n] = -1e30f;
        }
        float a = fmaxf(fmaxf(v[0], v[1]), fmaxf(v[2], v[3]));
        a = fmaxf(a, __shfl_xor(a, 1));
        a = fmaxf(a, __shfl_xor(a, 2));
        a = fmaxf(a, __shfl_xor(a, 4));
        a = fmaxf(a, __shfl_xor(a, 8));
        float mn = fmaxf(mrow[m][r], a);
        float al = fexp2(mrow[m][r] - mn);
        mrow[m][r] = mn;
        int prow = m * 16 + g * 4 + r;
        float rs = 0.f;
        #pragma unroll
        for (int n = 0; n < 4; ++n) {
          float p = fexp2(v[n] - mn);
          rs += p;
          Pw[w][prow * 72 + n * 16 + li] = (_Float16)p;
        }
        rs += __shfl_xor(rs, 1);
        rs += __shfl_xor(rs, 2);
        rs += __shfl_xor(rs, 4);
        rs += __shfl_xor(rs, 8);
        lrow[m][r] = lrow[m][r] * al + rs;
        #pragma unroll
        for (int n = 0; n < 4; ++n) o[m][n][r] *= al;
      }
    }
    // O += P V   (m: 2 q-tiles, n: 4 d-tiles, k = 64 keys)
    #pragma unroll
    for (int ks = 0; ks < 2; ++ks) {
      half8 pa[2];
      #pragma unroll
      for (int m = 0; m < 2; ++m)
        pa[m] = *(const half8*)(&Pw[w][(m * 16 + li) * 72 + ks * 32 + g * 8]);
      #pragma unroll
      for (int n = 0; n < 4; ++n) {
        int vr = n * 16 + li;
        half8 vf = *(const half8*)(Vs + vr * 64 + (((ks * 4 + g) ^ (vr & 7)) * 8));
        o[0][n] = __builtin_amdgcn_mfma_f32_16x16x32_f16(pa[0], vf, o[0][n], 0, 0, 0);
        o[1][n] = __builtin_amdgcn_mfma_f32_16x16x32_f16(pa[1], vf, o[1][n], 0, 0, 0);
      }
    }
    __syncthreads();
  }
  #pragma unroll
  for (int m = 0; m < 2; ++m) {
    #pragma unroll
    for (int r = 0; r < 4; ++r) {
      int qr = q0 + m * 16 + g * 4 + r;
      if (qr < SEQ) {
        float inv = frcp(lrow[m][r]);
        _Float16* yp = Y + (base + qr) * 1024 + h * 64 + li;
        #pragma unroll
        for (int n = 0; n < 4; ++n) yp[n * 16] = (_Float16)(o[m][n][r] * inv);
      }
    }
  }
}

extern "C" void kernel_launch(void* const* d_in, const int* in_sizes, int n_in,
                              void* d_out, int out_size, void* d_ws, size_t ws_size,
                              hipStream_t stream) {
  (void)in_sizes; (void)n_in; (void)out_size; (void)ws_size;
  const float* x      = (const float*)d_in[0];
  const float* w_qkv  = (const float*)d_in[1];
  const float* b_qkv  = (const float*)d_in[2];
  const float* w_proj = (const float*)d_in[3];
  const float* b_proj = (const float*)d_in[4];
  const float* ln1_g  = (const float*)d_in[5];
  const float* ln1_b  = (const float*)d_in[6];
  const float* ln2_g  = (const float*)d_in[7];
  const float* ln2_b  = (const float*)d_in[8];
  const float* w_fc1  = (const float*)d_in[9];
  const float* b_fc1  = (const float*)d_in[10];
  const float* w_fc2  = (const float*)d_in[11];
  const float* b_fc2  = (const float*)d_in[12];

  // workspace layout (bytes), total 159,121,408
  char* ws = (char*)d_ws;
  _Float16* Abuf = (_Float16*)ws;                          // [MPAD][1024] act fp16 (xn1 / xn2)
  _Float16* Wq   = (_Float16*)(ws + 19136512);             // weights fp16
  _Float16* Wp   = Wq + 3072 * 1024;
  _Float16* W1   = Wp + 1024 * 1024;
  _Float16* W2   = W1 + 4096 * 1024;
  _Float16* Qb   = (_Float16*)(ws + 44302336);             // [MPAD][3072] qkv fp16
  _Float16* Yb   = Qb + (long)MPAD * 3072;                 // [MPAD][1024] attn out fp16
  _Float16* Hb   = Qb;                                     // [MPAD][4096] fp16, reuses Qb+Yb
  float*    X1   = (float*)(ws + 120848384);               // [MPAD][1024] fp32 x+attn
  _Float16* Vtb  = (_Float16*)(ws + 120848384);            // [256][64][SEQP] fp16, 21 MB,
                                                           // overlays X1 (dead until proj)

  cvt_f16_kernel<<<1536, 256, 0, stream>>>(w_qkv, Wq, 3072 * 1024);
  cvt_f16_kernel<<<512,  256, 0, stream>>>(w_proj, Wp, 1024 * 1024);
  cvt_f16_kernel<<<2048, 256, 0, stream>>>(w_fc1, W1, 4096 * 1024);
  cvt_f16_kernel<<<2048, 256, 0, stream>>>(w_fc2, W2, 4096 * 1024);

  ln_kernel<<<MPAD, 256, 0, stream>>>(x, ln1_g, ln1_b, Abuf, MTOK);
  gemm_bt<0><<<dim3(73, 24), 256, 0, stream>>>(Abuf, Wq, b_qkv, nullptr, Qb, 3072, 1024);
  vt_kernel<<<dim3(NKT, 256), 256, 0, stream>>>(Qb, Vtb);
  attn_kernel<<<dim3(5, 256), 256, 0, stream>>>(Qb, Vtb, Yb);
  gemm_bt<2><<<dim3(73, 8), 256, 0, stream>>>(Yb, Wp, b_proj, x, X1, 1024, 1024);
  ln_kernel<<<MPAD, 256, 0, stream>>>(X1, ln2_g, ln2_b, Abuf, MTOK);
  gemm_bt<1><<<dim3(73, 32), 256, 0, stream>>>(Abuf, W1, b_fc1, nullptr, Hb, 4096, 1024);
  gemm_bt<2><<<dim3(73, 8), 256, 0, stream>>>(Hb, W2, b_fc2, X1, d_out, 1024, 4096);
}